// Round 13
// baseline (270.970 us; speedup 1.0000x reference)
//
#include <hip/hip_runtime.h>

#define E_TOTAL 200000
#define OUTD 5
#define NTILES 3125           // 200000 / 64 exactly
#define GRIDB 256             // persistent: 1 block per CU
#define WP_USHORTS 532480     // W0p (262144) + W1p (262144) + W2p (8192)
#define XBF_USHORTS 2560000   // 10000 * 256 bf16 copy of x
#define BUFB 65536u           // one A-buffer (64 rows x 512 cols x 2B)

typedef __attribute__((ext_vector_type(4))) float f32x4;
typedef __attribute__((ext_vector_type(16))) float f32x16;
typedef __attribute__((ext_vector_type(8))) __bf16 bf16x8;

static __device__ __forceinline__ unsigned short f2bf(float f) {
  union { float f; unsigned u; } v; v.f = f;
  unsigned u = v.u;
  unsigned r = (u + 0x7FFFu + ((u >> 16) & 1u)) >> 16;   // RNE
  return (unsigned short)r;
}
static __device__ __forceinline__ unsigned short f2bf_cast(float f) {
  __bf16 h = (__bf16)f;                                   // HW cvt, RNE
  return __builtin_bit_cast(unsigned short, h);
}

// ---------------------------------------------------------------------------
// Pack W0,W1 [512x512] into 32x32x16-bf16 fragment order:
//   off = ((wtile*32 + ks)*64 + lane)*8 + j, value = W[k][n]
// W2 [512x5] padded N=16 into 16x16x32 fragment order.
// ws layout (ushort): [0,262144) W0p | [262144,524288) W1p | [524288,532480) W2p
//                     [532480, +2560000) xbf (if ws_size permits)
// ---------------------------------------------------------------------------
__global__ __launch_bounds__(256) void pack_weights(
    const float* __restrict__ W0, const float* __restrict__ W1,
    const float* __restrict__ W2, unsigned short* __restrict__ wp) {
  int tid = blockIdx.x * 256 + threadIdx.x;
  if (tid < 2 * 262144) {
    int sel = tid >> 18;
    int t = tid & 262143;
    int n = t & 511, k = t >> 9;            // coalesced read along n
    const float* W = sel ? W1 : W0;
    float val = W[k * 512 + n];
    int ntile = n >> 5, ks = k >> 4;
    int lane = (((k >> 3) & 1) << 5) | (n & 31);
    int j = k & 7;
    int off = (((ntile * 32 + ks) * 64 + lane) << 3) | j;
    wp[sel * 262144 + off] = f2bf(val);
  } else {
    int t2 = tid - 524288;
    if (t2 < 8192) {                         // W2 padded N=5 -> 16
      int j = t2 & 7, lane = (t2 >> 3) & 63, k0 = t2 >> 9;
      int k = k0 * 32 + ((lane >> 4) << 3) + j;
      int n = lane & 15;
      float val = (n < OUTD) ? W2[k * OUTD + n] : 0.0f;
      wp[524288 + t2] = f2bf(val);
    }
  }
}

// fp32 x -> bf16 copy (one-shot, memory-bound)
__global__ __launch_bounds__(256) void convert_x(
    const float* __restrict__ x, unsigned short* __restrict__ xbf) {
  int i = blockIdx.x * 256 + threadIdx.x;    // 8 elems each
  if (i < 320000) {
    const float4 f0 = *(const float4*)(x + (size_t)i * 8);
    const float4 f1 = *(const float4*)(x + (size_t)i * 8 + 4);
    uint4 pk;
    pk.x = (unsigned)f2bf(f0.x) | ((unsigned)f2bf(f0.y) << 16);
    pk.y = (unsigned)f2bf(f0.z) | ((unsigned)f2bf(f0.w) << 16);
    pk.z = (unsigned)f2bf(f1.x) | ((unsigned)f2bf(f1.y) << 16);
    pk.w = (unsigned)f2bf(f1.z) | ((unsigned)f2bf(f1.w) << 16);
    *(uint4*)(xbf + (size_t)i * 8) = pk;
  }
}

// ---------------------------------------------------------------------------
// Persistent fused edge-MLP with async double-buffered staging.
// 256 blocks (1/CU), 512 threads (8 waves), 64-edge tiles, 12-13 tiles/block.
// LDS: 2 x [64][512] bf16 A/H buffers (2 x 65536 B, XOR-swz byte^=(row&7)<<4)
// + 1280 B obuf = 132352 B.
// Tile pipeline: at tile t's top, each wave issues 8 global_load_lds (16B,
// per-lane source chunk pre-XOR'd = same involution the reads use) staging
// tile t+GRIDB into the other buffer; the DMA drains at t's first barrier,
// ~13 us of k-loop later -> staging fully hidden, zero VALU cost.
// Per wave (operand-swapped, fg=w): features w*64..+63 (2 ft-tiles) x
// 64 edges (2 e-tiles): acc 4 x f32x16 (64 AGPR), 2 weight loads + 2
// ds_read_b128 + 4 MFMA per k-step, depth-1 prefetch, bias C-init; next
// phase's first weight frags hoisted before each epilogue barrier.
// No setprio (T5 null/negative in non-8-phase GEMM, m190).
// Layer 2: waves 0..3 x 16 edges, pair-mean __shfl_xor(.,1); feature-4
// written only by q==1.
// ---------------------------------------------------------------------------
template <int XBF>
__global__ __launch_bounds__(512, 2) void edge_mlp(
    const float* __restrict__ x, const unsigned short* __restrict__ xbf,
    const int* __restrict__ eidx,
    const float* __restrict__ b0, const float* __restrict__ b1,
    const float* __restrict__ b2, const unsigned short* __restrict__ wp,
    float* __restrict__ out) {
  __shared__ uint4 ldsv[8192 + 80];           // 131072 + 1280 B
  unsigned char* lds = (unsigned char*)ldsv;
  float* obuf = (float*)(lds + 2 * BUFB);     // 64*5 f32

  const int tid = threadIdx.x;
  const int lane = tid & 63;
  const int w = tid >> 6;                     // wave 0..7
  const int l31 = lane & 31, h = lane >> 5;
  const int l15 = lane & 15, q = lane >> 4;
  const unsigned sx31 = (unsigned)((l31 & 7) << 4);
  const unsigned short* w2b = wp + 524288 + (size_t)lane * 8;

  // async DMA staging: wave w stages rows w*8..w*8+7; LDS dest is linear
  // (wave-uniform base + lane*16); swizzle applied by XOR-ing the per-lane
  // SOURCE chunk (involution matches the read-side XOR).
#define ISSUE_STAGE(TT, BOFF)                                                  \
  {                                                                            \
    _Pragma("unroll")                                                          \
    for (int i_ = 0; i_ < 8; ++i_) {                                           \
      const int r_ = w * 8 + i_;                                               \
      const int e_ = (int)(TT) * 64 + r_;                                      \
      const unsigned short* gs_ =                                              \
          (lane < 32 ? xbf + (size_t)eidx[e_] * 256                            \
                     : xbf + (size_t)eidx[E_TOTAL + e_] * 256) +               \
          (((lane & 31) ^ (r_ & 7)) << 3);                                     \
      __builtin_amdgcn_global_load_lds(                                        \
          (const __attribute__((address_space(1))) unsigned int*)gs_,          \
          (__attribute__((address_space(3))) unsigned int*)(lds + (BOFF) +     \
                                                  (unsigned)r_ * 1024),        \
          16, 0, 0);                                                           \
    }                                                                          \
  }

  // synchronous fallback (no xbf workspace): f32 gather + cvt + LDS write
#define SYNC_STAGE(TT, BOFF)                                                   \
  {                                                                            \
    const int r_ = tid >> 3, p_ = tid & 7;                                     \
    const int e_ = (int)(TT) * 64 + r_;                                        \
    const int node_ = eidx[(p_ >> 2) * E_TOTAL + e_];                          \
    const unsigned rowb_ = (BOFF) + (unsigned)r_ * 1024;                       \
    const unsigned sxw_ = (unsigned)((r_ & 7) << 4);                           \
    const unsigned cb0_ = (unsigned)((p_ >> 2) * 512 + (p_ & 3) * 128);        \
    const float* s_ = x + (size_t)node_ * 256 + (p_ & 3) * 64;                 \
    _Pragma("unroll")                                                          \
    for (int jj = 0; jj < 8; ++jj) {                                           \
      const int kk = (jj + p_) & 7;                                            \
      const float4 f0 = *(const float4*)(s_ + kk * 8);                         \
      const float4 f1 = *(const float4*)(s_ + kk * 8 + 4);                     \
      uint4 pk;                                                                \
      pk.x = (unsigned)f2bf(f0.x) | ((unsigned)f2bf(f0.y) << 16);              \
      pk.y = (unsigned)f2bf(f0.z) | ((unsigned)f2bf(f0.w) << 16);              \
      pk.z = (unsigned)f2bf(f1.x) | ((unsigned)f2bf(f1.y) << 16);              \
      pk.w = (unsigned)f2bf(f1.z) | ((unsigned)f2bf(f1.w) << 16);              \
      *(uint4*)(lds + rowb_ + ((cb0_ + (unsigned)kk * 16) ^ sxw_)) = pk;       \
    }                                                                          \
  }

  unsigned t = blockIdx.x;
  unsigned boff = 0;
  if (XBF) ISSUE_STAGE(t, 0u)
  else     SYNC_STAGE(t, 0u)

  // L0 weight bases + first fragments
  const unsigned short* wbA = wp + (size_t)(w * 2) * 16384 + (size_t)lane * 8;
  const unsigned short* wbB = wbA + 16384;
  bf16x8 cwA = *(const bf16x8*)wbA;
  bf16x8 cwB = *(const bf16x8*)wbB;
  __syncthreads();                            // drains prologue staging

  for (;;) {
    const unsigned tn = t + GRIDB;
    if (XBF && tn < NTILES) ISSUE_STAGE(tn, boff ^ BUFB)

    // ===== hidden layers =====
#pragma unroll 1
    for (int L = 0; L < 2; ++L) {
      const float* bias = L ? b1 : b0;

      f32x16 aA0, aA1, aB0, aB1;              // acc[ftile][etile]
#define BINIT(ACC0, ACC1, F)                                                   \
      {                                                                        \
        _Pragma("unroll")                                                      \
        for (int qd = 0; qd < 4; ++qd) {                                       \
          const float4 bq = *(const float4*)(bias + w * 64 + (F) * 32 + 8 * qd + 4 * h); \
          _Pragma("unroll")                                                    \
          for (int rr = 0; rr < 4; ++rr) {                                     \
            (ACC0)[4 * qd + rr] = bq[rr];                                      \
            (ACC1)[4 * qd + rr] = bq[rr];                                      \
          }                                                                    \
        }                                                                      \
      }
      BINIT(aA0, aA1, 0) BINIT(aB0, aB1, 1)
#undef BINIT

#pragma unroll 2
      for (int ks = 0; ks < 32; ++ks) {
        const int kp = (ks + 1) & 31;         // depth-1 prefetch, branchless wrap
        bf16x8 nwA = *(const bf16x8*)(wbA + kp * 512);
        bf16x8 nwB = *(const bf16x8*)(wbB + kp * 512);
        const unsigned cb = (unsigned)(ks * 32 + h * 16);
        bf16x8 e0 = *(const bf16x8*)(lds + boff + (unsigned)l31 * 1024 + (cb ^ sx31));
        bf16x8 e1 = *(const bf16x8*)(lds + boff + (unsigned)(32 + l31) * 1024 + (cb ^ sx31));
        aA0 = __builtin_amdgcn_mfma_f32_32x32x16_bf16(cwA, e0, aA0, 0, 0, 0);
        aB0 = __builtin_amdgcn_mfma_f32_32x32x16_bf16(cwB, e0, aB0, 0, 0, 0);
        aA1 = __builtin_amdgcn_mfma_f32_32x32x16_bf16(cwA, e1, aA1, 0, 0, 0);
        aB1 = __builtin_amdgcn_mfma_f32_32x32x16_bf16(cwB, e1, aB1, 0, 0, 0);
        cwA = nwA; cwB = nwB;
      }

      // hoist next phase's first weight fragments BEFORE the epilogue barrier
      if (L == 0) {
        wbA = wp + 262144 + (size_t)(w * 2) * 16384 + (size_t)lane * 8;
        wbB = wbA + 16384;
        cwA = *(const bf16x8*)wbA;
        cwB = *(const bf16x8*)wbB;
      } else {
        wbA = wp + (size_t)(w * 2) * 16384 + (size_t)lane * 8;   // next tile L0
        wbB = wbA + 16384;
        cwA = *(const bf16x8*)wbA;
        cwB = *(const bf16x8*)wbB;
      }

      __syncthreads();  // all waves done reading A/H; only AGPR acc lives across

      // relu + cvt + write H over A, b64 quads.
      // C layout: col(lane&31)=edge, row(reg)=(reg&3)+8*(reg>>2)+4h = feature
      // quad byte col = 128w + 64F + 16qd + 8h, XOR (edge&7)<<4.
#define EPI_TILE(ACC, F, ET)                                                   \
      {                                                                        \
        const unsigned rowb = boff + (unsigned)((ET) * 32 + l31) * 1024;       \
        const unsigned cbase = (unsigned)(128 * w + 64 * (F) + 8 * h);         \
        _Pragma("unroll")                                                      \
        for (int qd = 0; qd < 4; ++qd) {                                       \
          uint2 pk2;                                                           \
          pk2.x = (unsigned)f2bf_cast(fmaxf((ACC)[4 * qd + 0], 0.f)) |         \
                  ((unsigned)f2bf_cast(fmaxf((ACC)[4 * qd + 1], 0.f)) << 16);  \
          pk2.y = (unsigned)f2bf_cast(fmaxf((ACC)[4 * qd + 2], 0.f)) |         \
                  ((unsigned)f2bf_cast(fmaxf((ACC)[4 * qd + 3], 0.f)) << 16);  \
          *(uint2*)(lds + rowb + ((cbase + 16u * qd) ^ sx31)) = pk2;           \
        }                                                                      \
      }
      EPI_TILE(aA0, 0, 0) EPI_TILE(aA1, 0, 1)
      EPI_TILE(aB0, 1, 0) EPI_TILE(aB1, 1, 1)
#undef EPI_TILE
      __syncthreads();
    }

    // ===== layer 2 (swapped): waves 0..3 -> edges w*16..+15, N=16 padded ====
    if (w < 4) {
      f32x4 acc2; acc2[0] = 0.f; acc2[1] = 0.f; acc2[2] = 0.f; acc2[3] = 0.f;
      const unsigned row = (unsigned)(w * 16 + l15);   // edge (B-operand col)
      const unsigned rsx = (row & 7) << 4;
#pragma unroll
      for (int k0 = 0; k0 < 16; ++k0) {
        bf16x8 eF = *(const bf16x8*)(lds + boff + row * 1024 +
                                     (((unsigned)(k0 * 64 + q * 16)) ^ rsx));
        bf16x8 wF = *(const bf16x8*)(w2b + k0 * 512);
        acc2 = __builtin_amdgcn_mfma_f32_16x16x32_bf16(wF, eF, acc2, 0, 0, 0);
      }
      const int e = w * 16 + l15;
#pragma unroll
      for (int r = 0; r < 4; ++r) {
        const float s = __shfl_xor(acc2[r], 1);
        const float m = 0.5f * (acc2[r] + s);
        if (q == 0) {
          obuf[e * OUTD + r] = m + b2[r];
        } else if (q == 1 && r == 0) {        // feature 4 ONLY from q==1
          obuf[e * OUTD + 4] = m + b2[4];
        }
      }
    }
    __syncthreads();

    // ===== coalesced out store (20 full 64B lines) =====
    {
      uint4* dst = (uint4*)(out + (size_t)t * 320);
      const uint4* sob = (const uint4*)obuf;
      if (tid < 80) dst[tid] = sob[tid];
    }

    if (tn >= NTILES) break;
    if (!XBF) { SYNC_STAGE(tn, boff ^ BUFB) __syncthreads(); }
    t = tn;
    boff ^= BUFB;
  }
#undef ISSUE_STAGE
#undef SYNC_STAGE
}

extern "C" void kernel_launch(void* const* d_in, const int* in_sizes, int n_in,
                              void* d_out, int out_size, void* d_ws, size_t ws_size,
                              hipStream_t stream) {
  const float* x  = (const float*)d_in[0];
  const int* eidx = (const int*)d_in[1];
  const float* W0 = (const float*)d_in[2];
  const float* b0 = (const float*)d_in[3];
  const float* W1 = (const float*)d_in[4];
  const float* b1 = (const float*)d_in[5];
  const float* W2 = (const float*)d_in[6];
  const float* b2 = (const float*)d_in[7];
  float* out = (float*)d_out;
  unsigned short* wp = (unsigned short*)d_ws;
  if (ws_size < (size_t)WP_USHORTS * 2) return;   // ~1.04 MB minimum

  pack_weights<<<2080, 256, 0, stream>>>(W0, W1, W2, wp);
  if (ws_size >= (size_t)(WP_USHORTS + XBF_USHORTS) * 2) {
    unsigned short* xbf = wp + WP_USHORTS;
    convert_x<<<1250, 256, 0, stream>>>(x, xbf);
    edge_mlp<1><<<GRIDB, 512, 0, stream>>>(x, xbf, eidx, b0, b1, b2, wp, out);
  } else {
    edge_mlp<0><<<GRIDB, 512, 0, stream>>>(x, nullptr, eidx, b0, b1, b2, wp, out);
  }
}

// Round 14
// 236.317 us; speedup vs baseline: 1.1466x; 1.1466x over previous
//
#include <hip/hip_runtime.h>

#define E_TOTAL 200000
#define OUTD 5
#define NTILES 3125           // 200000 / 64 exactly, no tail
#define WP_USHORTS 532480     // W0p (262144) + W1p (262144) + W2p (8192)
#define XBF_USHORTS 2560000   // 10000 * 256 bf16 copy of x

typedef __attribute__((ext_vector_type(4))) float f32x4;
typedef __attribute__((ext_vector_type(16))) float f32x16;
typedef __attribute__((ext_vector_type(8))) __bf16 bf16x8;

static __device__ __forceinline__ unsigned short f2bf(float f) {
  union { float f; unsigned u; } v; v.f = f;
  unsigned u = v.u;
  unsigned r = (u + 0x7FFFu + ((u >> 16) & 1u)) >> 16;   // RNE
  return (unsigned short)r;
}
static __device__ __forceinline__ unsigned short f2bf_cast(float f) {
  __bf16 h = (__bf16)f;                                   // HW cvt, RNE
  return __builtin_bit_cast(unsigned short, h);
}

// ---------------------------------------------------------------------------
// Pack W0,W1 [512x512] into 32x32x16-bf16 fragment order:
//   off = ((wtile*32 + ks)*64 + lane)*8 + j, value = W[k][n]
// W2 [512x5] padded N=16 into 16x16x32 fragment order.
// ws layout (ushort): [0,262144) W0p | [262144,524288) W1p | [524288,532480) W2p
//                     [532480, +2560000) xbf (if ws_size permits)
// ---------------------------------------------------------------------------
__global__ __launch_bounds__(256) void pack_weights(
    const float* __restrict__ W0, const float* __restrict__ W1,
    const float* __restrict__ W2, unsigned short* __restrict__ wp) {
  int tid = blockIdx.x * 256 + threadIdx.x;
  if (tid < 2 * 262144) {
    int sel = tid >> 18;
    int t = tid & 262143;
    int n = t & 511, k = t >> 9;            // coalesced read along n
    const float* W = sel ? W1 : W0;
    float val = W[k * 512 + n];
    int ntile = n >> 5, ks = k >> 4;
    int lane = (((k >> 3) & 1) << 5) | (n & 31);
    int j = k & 7;
    int off = (((ntile * 32 + ks) * 64 + lane) << 3) | j;
    wp[sel * 262144 + off] = f2bf(val);
  } else {
    int t2 = tid - 524288;
    if (t2 < 8192) {                         // W2 padded N=5 -> 16
      int j = t2 & 7, lane = (t2 >> 3) & 63, k0 = t2 >> 9;
      int k = k0 * 32 + ((lane >> 4) << 3) + j;
      int n = lane & 15;
      float val = (n < OUTD) ? W2[k * OUTD + n] : 0.0f;
      wp[524288 + t2] = f2bf(val);
    }
  }
}

// fp32 x -> bf16 copy (one-shot, memory-bound)
__global__ __launch_bounds__(256) void convert_x(
    const float* __restrict__ x, unsigned short* __restrict__ xbf) {
  int i = blockIdx.x * 256 + threadIdx.x;    // 8 elems each
  if (i < 320000) {
    const float4 f0 = *(const float4*)(x + (size_t)i * 8);
    const float4 f1 = *(const float4*)(x + (size_t)i * 8 + 4);
    uint4 pk;
    pk.x = (unsigned)f2bf(f0.x) | ((unsigned)f2bf(f0.y) << 16);
    pk.y = (unsigned)f2bf(f0.z) | ((unsigned)f2bf(f0.w) << 16);
    pk.z = (unsigned)f2bf(f1.x) | ((unsigned)f2bf(f1.y) << 16);
    pk.w = (unsigned)f2bf(f1.z) | ((unsigned)f2bf(f1.w) << 16);
    *(uint4*)(xbf + (size_t)i * 8) = pk;
  }
}

// ---------------------------------------------------------------------------
// Fused edge-MLP, operand-swapped, 4-wave blocks, K-PHASE STAGGERED:
// identical to the R9 238-us kernel EXCEPT each block iterates K starting at
// ks0 = (blockIdx>>3)&31 (wrapped). All 32 CUs of an XCD thus read DIFFERENT
// 16-feature K-slices of the packed weights at any instant -> the weight
// stream spreads across all L2 slices instead of funneling into the few
// holding the "current" region (same-address contention). Phase is shared
// across XCDs (private L2s) and by co-resident pairs (b, b+256) -> L1 reuse
// kept. K-accumulation order is irrelevant (bias preloaded in C-init).
// One block = 64 edges, 256 threads (4 waves), 2 blocks/CU.
// Wave w: features w*128..+127 (4 ft-tiles) x 64 edges (2 e-tiles);
// acc 8 x f32x16 (128 AGPR), depth-1 weight prefetch, ~104 VGPR.
// LDS: [64][512] bf16 A/H (65536 B, swizzle byte^=(row&7)<<4) + 1280 B obuf.
// Layer 2 (stagger k0 likewise): 4 waves x 16 edges, pair-mean
// __shfl_xor(.,1); feature-4 written only by q==1.
// ---------------------------------------------------------------------------
template <int XBF>
__global__ __launch_bounds__(256, 2) void edge_mlp(
    const float* __restrict__ x, const unsigned short* __restrict__ xbf,
    const int* __restrict__ eidx,
    const float* __restrict__ b0, const float* __restrict__ b1,
    const float* __restrict__ b2, const unsigned short* __restrict__ wp,
    float* __restrict__ out) {
  __shared__ uint4 ldsv[4096 + 80];           // 65536 + 1280 B
  unsigned char* lds = (unsigned char*)ldsv;
  float* obuf = (float*)(lds + 65536);        // 64*5 f32

  const int tid = threadIdx.x;
  const int lane = tid & 63;
  const int w = tid >> 6;                     // wave 0..3
  const int l31 = lane & 31, h = lane >> 5;
  const int l15 = lane & 15, q = lane >> 4;
  const unsigned t = blockIdx.x;
  const int phase = ((int)t >> 3) & 31;       // per-XCD-position K stagger

  // ---- stage gathered inputs: A[64][512] bf16, cols 0..255 = x[src], 256..511 = x[dst]
  {
    const int p = tid & 7;                    // 8 threads per row, 2 passes
#pragma unroll
    for (int pass = 0; pass < 2; ++pass) {
      const int r = (tid >> 3) + 32 * pass;
      const int e = (int)t * 64 + r;          // grid exact
      const int node = eidx[(p >> 2) * E_TOTAL + e];
      const unsigned rowb = (unsigned)r * 1024;
      const unsigned sx = (unsigned)((r & 7) << 4);
      const unsigned cb0 = (unsigned)((p >> 2) * 512 + (p & 3) * 128);
      if (XBF) {
        const unsigned short* s = xbf + (size_t)node * 256 + (p & 3) * 64;
#pragma unroll
        for (int jj = 0; jj < 8; ++jj) {
          const int kk = (jj + p) & 7;        // phase by p: conflict-spread writes
          uint4 pk = *(const uint4*)(s + kk * 8);
          *(uint4*)(lds + rowb + ((cb0 + (unsigned)kk * 16) ^ sx)) = pk;
        }
      } else {
        const float* s = x + (size_t)node * 256 + (p & 3) * 64;
#pragma unroll
        for (int jj = 0; jj < 8; ++jj) {
          const int kk = (jj + p) & 7;
          const float4 f0 = *(const float4*)(s + kk * 8);
          const float4 f1 = *(const float4*)(s + kk * 8 + 4);
          uint4 pk;
          pk.x = (unsigned)f2bf(f0.x) | ((unsigned)f2bf(f0.y) << 16);
          pk.y = (unsigned)f2bf(f0.z) | ((unsigned)f2bf(f0.w) << 16);
          pk.z = (unsigned)f2bf(f1.x) | ((unsigned)f2bf(f1.y) << 16);
          pk.w = (unsigned)f2bf(f1.z) | ((unsigned)f2bf(f1.w) << 16);
          *(uint4*)(lds + rowb + ((cb0 + (unsigned)kk * 16) ^ sx)) = pk;
        }
      }
    }
  }
  __syncthreads();

  const unsigned sx31 = (unsigned)((l31 & 7) << 4);  // k-loop read & epi swizzle

  // ===== hidden layers =====
#pragma unroll 1
  for (int L = 0; L < 2; ++L) {
    const unsigned short* wl = wp + L * 262144;
    const unsigned short* wbA = wl + (size_t)(4 * w) * 16384 + (size_t)lane * 8;
    const unsigned short* wbB = wbA + 16384;
    const unsigned short* wbC = wbA + 32768;
    const unsigned short* wbD = wbA + 49152;
    const float* bias = L ? b1 : b0;

    // bias C-init: reg 4*qd+rr -> feature w*128 + F*32 + 8*qd + 4*h + rr
    f32x16 aA0, aA1, aB0, aB1, aC0, aC1, aD0, aD1;
#define BINIT(ACC0, ACC1, F)                                                   \
    {                                                                          \
      _Pragma("unroll")                                                        \
      for (int qd = 0; qd < 4; ++qd) {                                         \
        const float4 bq = *(const float4*)(bias + w * 128 + (F) * 32 + 8 * qd + 4 * h); \
        _Pragma("unroll")                                                      \
        for (int rr = 0; rr < 4; ++rr) {                                       \
          (ACC0)[4 * qd + rr] = bq[rr];                                        \
          (ACC1)[4 * qd + rr] = bq[rr];                                        \
        }                                                                      \
      }                                                                        \
    }
    BINIT(aA0, aA1, 0) BINIT(aB0, aB1, 1) BINIT(aC0, aC1, 2) BINIT(aD0, aD1, 3)
#undef BINIT

    bf16x8 cwA = *(const bf16x8*)(wbA + phase * 512);
    bf16x8 cwB = *(const bf16x8*)(wbB + phase * 512);
    bf16x8 cwC = *(const bf16x8*)(wbC + phase * 512);
    bf16x8 cwD = *(const bf16x8*)(wbD + phase * 512);

#pragma unroll 2
    for (int i = 0; i < 32; ++i) {
      const int ks = (i + phase) & 31;        // staggered K order (sum-invariant)
      const int kp = (ks + 1) & 31;           // depth-1 prefetch, branchless wrap
      bf16x8 nwA = *(const bf16x8*)(wbA + kp * 512);
      bf16x8 nwB = *(const bf16x8*)(wbB + kp * 512);
      bf16x8 nwC = *(const bf16x8*)(wbC + kp * 512);
      bf16x8 nwD = *(const bf16x8*)(wbD + kp * 512);
      const unsigned cb = (unsigned)(ks * 32 + h * 16);
      bf16x8 e0 = *(const bf16x8*)(lds + (unsigned)l31 * 1024 + (cb ^ sx31));
      bf16x8 e1 = *(const bf16x8*)(lds + (unsigned)(32 + l31) * 1024 + (cb ^ sx31));
      __builtin_amdgcn_s_setprio(1);
      aA0 = __builtin_amdgcn_mfma_f32_32x32x16_bf16(cwA, e0, aA0, 0, 0, 0);
      aB0 = __builtin_amdgcn_mfma_f32_32x32x16_bf16(cwB, e0, aB0, 0, 0, 0);
      aC0 = __builtin_amdgcn_mfma_f32_32x32x16_bf16(cwC, e0, aC0, 0, 0, 0);
      aD0 = __builtin_amdgcn_mfma_f32_32x32x16_bf16(cwD, e0, aD0, 0, 0, 0);
      aA1 = __builtin_amdgcn_mfma_f32_32x32x16_bf16(cwA, e1, aA1, 0, 0, 0);
      aB1 = __builtin_amdgcn_mfma_f32_32x32x16_bf16(cwB, e1, aB1, 0, 0, 0);
      aC1 = __builtin_amdgcn_mfma_f32_32x32x16_bf16(cwC, e1, aC1, 0, 0, 0);
      aD1 = __builtin_amdgcn_mfma_f32_32x32x16_bf16(cwD, e1, aD1, 0, 0, 0);
      __builtin_amdgcn_s_setprio(0);
      cwA = nwA; cwB = nwB; cwC = nwC; cwD = nwD;
    }

    __syncthreads();   // all waves done reading A/H; only AGPR acc lives across

    // relu + cvt + write H over A, b64 quads.
    // C layout: col(lane&31)=edge, row(reg)=(reg&3)+8*(reg>>2)+4h = feature
    // quad byte col = 256w + 64*F + 16qd + 8h, XOR (edge&7)<<4.
#define EPI_TILE(ACC, F, ET)                                                   \
    {                                                                          \
      const unsigned rowb = (unsigned)((ET) * 32 + l31) * 1024;                \
      const unsigned cbase = (unsigned)(256 * w + 64 * (F) + 8 * h);           \
      _Pragma("unroll")                                                        \
      for (int qd = 0; qd < 4; ++qd) {                                         \
        uint2 pk2;                                                             \
        pk2.x = (unsigned)f2bf_cast(fmaxf((ACC)[4 * qd + 0], 0.f)) |           \
                ((unsigned)f2bf_cast(fmaxf((ACC)[4 * qd + 1], 0.f)) << 16);    \
        pk2.y = (unsigned)f2bf_cast(fmaxf((ACC)[4 * qd + 2], 0.f)) |           \
                ((unsigned)f2bf_cast(fmaxf((ACC)[4 * qd + 3], 0.f)) << 16);    \
        *(uint2*)(lds + rowb + ((cbase + 16u * qd) ^ sx31)) = pk2;             \
      }                                                                        \
    }
    EPI_TILE(aA0, 0, 0) EPI_TILE(aA1, 0, 1)
    EPI_TILE(aB0, 1, 0) EPI_TILE(aB1, 1, 1)
    EPI_TILE(aC0, 2, 0) EPI_TILE(aC1, 2, 1)
    EPI_TILE(aD0, 3, 0) EPI_TILE(aD1, 3, 1)
#undef EPI_TILE
    __syncthreads();
  }

  // ===== layer 2 (swapped, staggered): wave w -> edges w*16..+15, N=16 pad ==
  {
    f32x4 acc2; acc2[0] = 0.f; acc2[1] = 0.f; acc2[2] = 0.f; acc2[3] = 0.f;
    const unsigned short* w2b = wp + 524288 + (size_t)lane * 8;
    const unsigned row = (unsigned)(w * 16 + l15);     // edge (B-operand col)
    const unsigned rsx = (row & 7) << 4;
    const int ph16 = phase & 15;
#pragma unroll
    for (int i = 0; i < 16; ++i) {
      const int k0 = (i + ph16) & 15;         // staggered (sum-invariant)
      bf16x8 eF = *(const bf16x8*)(lds + row * 1024 + (((unsigned)(k0 * 64 + q * 16)) ^ rsx));
      bf16x8 wF = *(const bf16x8*)(w2b + k0 * 512);
      acc2 = __builtin_amdgcn_mfma_f32_16x16x32_bf16(wF, eF, acc2, 0, 0, 0);
    }
    // C: col(l15)=edge, row(q*4+r)=feature. Pair-mean across edges (e, e^1).
    const int e = w * 16 + l15;
#pragma unroll
    for (int r = 0; r < 4; ++r) {
      const float s = __shfl_xor(acc2[r], 1);
      const float m = 0.5f * (acc2[r] + s);
      if (q == 0) {
        obuf[e * OUTD + r] = m + b2[r];
      } else if (q == 1 && r == 0) {          // feature 4 ONLY from q==1
        obuf[e * OUTD + 4] = m + b2[4];
      }
    }
  }
  __syncthreads();

  // ===== coalesced out store (full 64B lines; 64*5*4B = 20 lines) =====
  {
    uint4* dst = (uint4*)(out + (size_t)t * 320);
    const uint4* sob = (const uint4*)obuf;
    if (tid < 80) dst[tid] = sob[tid];
  }
}

extern "C" void kernel_launch(void* const* d_in, const int* in_sizes, int n_in,
                              void* d_out, int out_size, void* d_ws, size_t ws_size,
                              hipStream_t stream) {
  const float* x  = (const float*)d_in[0];
  const int* eidx = (const int*)d_in[1];
  const float* W0 = (const float*)d_in[2];
  const float* b0 = (const float*)d_in[3];
  const float* W1 = (const float*)d_in[4];
  const float* b1 = (const float*)d_in[5];
  const float* W2 = (const float*)d_in[6];
  const float* b2 = (const float*)d_in[7];
  float* out = (float*)d_out;
  unsigned short* wp = (unsigned short*)d_ws;
  if (ws_size < (size_t)WP_USHORTS * 2) return;   // ~1.04 MB minimum

  pack_weights<<<2080, 256, 0, stream>>>(W0, W1, W2, wp);
  if (ws_size >= (size_t)(WP_USHORTS + XBF_USHORTS) * 2) {
    unsigned short* xbf = wp + WP_USHORTS;
    convert_x<<<1250, 256, 0, stream>>>(x, xbf);
    edge_mlp<1><<<NTILES, 256, 0, stream>>>(x, xbf, eidx, b0, b1, b2, wp, out);
  } else {
    edge_mlp<0><<<NTILES, 256, 0, stream>>>(x, nullptr, eidx, b0, b1, b2, wp, out);
  }
}